// Round 12
// baseline (819.893 us; speedup 1.0000x reference)
//
#include <hip/hip_runtime.h>
#include <hip/hip_bf16.h>

// VQ-VAE vector quantizer, MI355X. z:(16,512,64,64) f32, codebook:(1024,512) f32.
// d_out f32: z_q (33554432), loss (1), idx (65536).
// R12 = R11 pipeline + 6 scratch-only ablation dispatches of k1 (diagnostic).

typedef _Float16 h8 __attribute__((ext_vector_type(8)));
typedef float f32x16 __attribute__((ext_vector_type(16)));

#define OUT_LOSS  33554432
#define OUT_IDX   33554433
#define MARGIN_T  0.15f

__device__ __forceinline__ void gload_lds16(const void* g, void* l) {
  __builtin_amdgcn_global_load_lds(
      (const __attribute__((address_space(1))) void*)g,
      (__attribute__((address_space(3))) void*)l, 16, 0, 0);
}

// ---- K0: cb fp32 -> fp16, fold-ordered 0.5||c||^2 table, workspace init ------
__global__ __launch_bounds__(64) void k0_prep(
    const float* __restrict__ cb, unsigned short* __restrict__ cb16,
    float* __restrict__ cnp, int* __restrict__ counters, float* __restrict__ loss_acc,
    int* __restrict__ idx_ws, unsigned long long* __restrict__ packed_ws)
{
  const int r = blockIdx.x, l = threadIdx.x;
  const float* row = cb + (size_t)r * 512;
  float4 a  = *(const float4*)(row + l * 8);
  float4 b4 = *(const float4*)(row + l * 8 + 4);
  h8 hv;
  hv[0] = (_Float16)a.x;  hv[1] = (_Float16)a.y;  hv[2] = (_Float16)a.z;  hv[3] = (_Float16)a.w;
  hv[4] = (_Float16)b4.x; hv[5] = (_Float16)b4.y; hv[6] = (_Float16)b4.z; hv[7] = (_Float16)b4.w;
  *reinterpret_cast<h8*>(cb16 + (size_t)r * 512 + l * 8) = hv;
  float s = a.x*a.x + a.y*a.y + a.z*a.z + a.w*a.w
          + b4.x*b4.x + b4.y*b4.y + b4.z*b4.z + b4.w*b4.w;
  #pragma unroll
  for (int off = 1; off < 64; off <<= 1) s += __shfl_xor(s, off);
  if (l == 0) {
    int jr = r & 31, c = r >> 5;
    int khalf = (jr >> 2) & 1;
    int pat = jr - (khalf << 2);
    int rr2 = (pat & 3) + ((pat >> 3) << 2);
    cnp[(c << 5) + (khalf << 4) + rr2] = 0.5f * s;
  }
  const int pix = (r << 6) + l;
  idx_ws[pix] = (int)0x80000000;
  packed_ws[pix] = ~0ull;
  if (r == 0 && l < 16) counters[l] = 0;
  if (r == 0 && l == 0) *loss_acc = 0.f;
}

// ======================= common k1 body pieces (shared) ========================
#define K1_IDS \
  const int tid   = threadIdx.x; \
  const int lane  = tid & 63; \
  const int wave  = tid >> 6; \
  const int pxl   = lane & 31; \
  const int khalf = lane >> 5; \
  const int px0   = blockIdx.x << 7; \
  const int b     = px0 >> 12; \
  const int hw0   = px0 & 4095; \
  const char* cbB = reinterpret_cast<const char*>(cb16); \
  const int laneoff = pxl * 1024 + khalf * 16;

#define K1_BFRAG \
  h8 bfrag[32]; \
  { \
    const float* zl = z + ((size_t)(b * 512 + khalf * 8)) * 4096 + hw0 + (wave << 5) + pxl; \
    _Pragma("unroll") \
    for (int s = 0; s < 32; ++s) { \
      const float* zs = zl + (size_t)s * 16 * 4096; \
      h8 hv; \
      _Pragma("unroll") \
      for (int e = 0; e < 8; ++e) hv[e] = (_Float16)zs[(size_t)e * 4096]; \
      bfrag[s] = hv; \
    } \
  }

#define K1_FOLD(CC) \
  { \
    const float* cl = cn_lds + ((CC) << 5) + (khalf << 4); \
    float4 q0 = *(const float4*)(cl);     float4 q1 = *(const float4*)(cl + 4); \
    float4 q2 = *(const float4*)(cl + 8); float4 q3 = *(const float4*)(cl + 12); \
    const float cn[16] = {q0.x,q0.y,q0.z,q0.w, q1.x,q1.y,q1.z,q1.w, \
                          q2.x,q2.y,q2.z,q2.w, q3.x,q3.y,q3.z,q3.w}; \
    float sc[16]; \
    _Pragma("unroll") \
    for (int r = 0; r < 16; ++r) sc[r] = cn[r] - (acca[r] + accb[r]); \
    float mn = sc[0]; \
    _Pragma("unroll") \
    for (int r = 1; r < 16; ++r) mn = fminf(mn, sc[r]); \
    if (__ballot(mn < v3)) { \
      const int jbase = ((CC) << 5) + (khalf << 2); \
      _Pragma("unroll") \
      for (int r = 0; r < 16; ++r) { \
        int j = jbase + ((r & 3) + ((r >> 2) << 3)); \
        float s = sc[r]; \
        bool c0 = s < v0, c1 = s < v1, c2 = s < v2, c3 = s < v3; \
        v3 = c2 ? v2 : (c3 ? s : v3);  i3 = c2 ? i2 : (c3 ? j : i3); \
        v2 = c1 ? v1 : (c2 ? s : v2);  i2 = c1 ? i1 : (c2 ? j : i2); \
        v1 = c0 ? v0 : (c1 ? s : v1);  i1 = c0 ? i0 : (c1 ? j : i1); \
        v0 = c0 ? s  : v0;             i0 = c0 ? j  : i0; \
      } \
    } \
    _Pragma("unroll") \
    for (int i = 0; i < 16; ++i) { acca[i] = 0.f; accb[i] = 0.f; } \
  }

#define K1_MERGE \
  { \
    float ow0 = __shfl_xor(v0, 32), ow1 = __shfl_xor(v1, 32), \
          ow2 = __shfl_xor(v2, 32), ow3 = __shfl_xor(v3, 32); \
    int   oj0 = __shfl_xor(i0, 32), oj1 = __shfl_xor(i1, 32), \
          oj2 = __shfl_xor(i2, 32), oj3 = __shfl_xor(i3, 32); \
    const float ow[4] = {ow0, ow1, ow2, ow3}; \
    const int   oj[4] = {oj0, oj1, oj2, oj3}; \
    _Pragma("unroll") \
    for (int k = 0; k < 4; ++k) { \
      float ov = ow[k]; int oi = oj[k]; \
      bool c0 = ov < v0, c1 = ov < v1, c2 = ov < v2, c3 = ov < v3; \
      v3 = c2 ? v2 : (c3 ? ov : v3);  i3 = c2 ? i2 : (c3 ? oi : i3); \
      v2 = c1 ? v1 : (c2 ? ov : v2);  i2 = c1 ? i1 : (c2 ? oi : i2); \
      v1 = c0 ? v0 : (c1 ? ov : v1);  i1 = c0 ? i0 : (c1 ? oi : i1); \
      v0 = c0 ? ov : v0;              i0 = c0 ? oi : i0; \
    } \
  }

#define K1_EMIT(IDXP, FLAGP, PAIRP, CTRP, MASKED) \
  { \
    const int pix = px0 + (wave << 5) + lane; \
    bool sane = (v0 == v0) && (v3 == v3) && ((unsigned)i0 < 1024u); \
    bool unfl = sane && (v1 - v0 >= MARGIN_T); \
    bool quad = sane && !unfl && (v3 - v0 >= MARGIN_T); \
    bool qpred = (lane < 32) && quad; \
    bool fpred = (lane < 32) && !unfl && !quad; \
    if (lane < 32) (IDXP)[pix] = unfl ? i0 : (int)0x80000000; \
    unsigned long long qm = __ballot(qpred); \
    if (qm) { \
      int leader = __ffsll(qm) - 1; \
      int base = 0; \
      if (lane == leader) base = atomicAdd(&(CTRP)[1], __popcll(qm)); \
      base = __shfl(base, leader); \
      if (qpred) { \
        int pos = __popcll(qm & ((1ull << lane) - 1ull)); \
        int wi = MASKED ? ((base + pos) & 65535) : (base + pos); \
        (PAIRP)[wi] = (unsigned long long)(unsigned)pix \
            | ((unsigned long long)(unsigned)i0 << 16) \
            | ((unsigned long long)(unsigned)i1 << 26) \
            | ((unsigned long long)(unsigned)i2 << 36) \
            | ((unsigned long long)(unsigned)i3 << 46); \
      } \
    } \
    unsigned long long fm = __ballot(fpred); \
    if (fm) { \
      int leader = __ffsll(fm) - 1; \
      int base = 0; \
      if (lane == leader) base = atomicAdd(&(CTRP)[0], __popcll(fm)); \
      base = __shfl(base, leader); \
      if (fpred) { \
        int pos = __popcll(fm & ((1ull << lane) - 1ull)); \
        int wi = MASKED ? ((base + pos) & 65535) : (base + pos); \
        (FLAGP)[wi] = pix; \
      } \
    } \
  }

// ---- K1 real (identical to R11) ----------------------------------------------
__global__ __launch_bounds__(256, 2) void k1_main(
    const float* __restrict__ z, const unsigned short* __restrict__ cb16,
    const float* __restrict__ cnp,
    int* __restrict__ idx_ws, int* __restrict__ flaglist,
    unsigned long long* __restrict__ pairlist, int* __restrict__ counters)
{
  extern __shared__ char smem[];
  float* cn_lds = reinterpret_cast<float*>(smem + 49152);
  K1_IDS
  #pragma unroll
  for (int i = 0; i < 4; ++i)
    gload_lds16(cbB + laneoff + wave * 128 + i * 32, smem + wave * 4096 + i * 1024);
  #pragma unroll
  for (int i = 0; i < 4; ++i)
    gload_lds16(cbB + 512 + laneoff + wave * 128 + i * 32, smem + 16384 + wave * 4096 + i * 1024);
  K1_BFRAG
  for (int i = tid; i < 1024; i += 256) cn_lds[i] = cnp[i];
  __syncthreads();

  float v0 = INFINITY, v1 = INFINITY, v2 = INFINITY, v3 = INFINITY;
  int   i0 = 0, i1 = 0, i2 = 0, i3 = 0;
  f32x16 acca, accb;
  #pragma unroll
  for (int i = 0; i < 16; ++i) { acca[i] = 0.f; accb[i] = 0.f; }
  char* p0 = smem; char* p1 = smem + 16384; char* p2 = smem + 32768;

  for (int c = 0; c < 32; ++c) {
    const bool pf = (c < 31);
    asm volatile("s_waitcnt vmcnt(4)" ::: "memory");
    __builtin_amdgcn_s_barrier();
    __builtin_amdgcn_sched_barrier(0);
    if (pf) {
      const char* src = cbB + (c + 1) * 32768 + laneoff + wave * 128;
      #pragma unroll
      for (int i = 0; i < 4; ++i) gload_lds16(src + i * 32, p2 + wave * 4096 + i * 1024);
    }
    {
      const char* ab = p0 + (pxl << 4) + (khalf << 9);
      h8 f[16];
      #pragma unroll
      for (int q = 0; q < 16; ++q) f[q] = *reinterpret_cast<const h8*>(ab + (q << 10));
      __builtin_amdgcn_s_setprio(1);
      #pragma unroll
      for (int q = 0; q < 8; ++q) {
        acca = __builtin_amdgcn_mfma_f32_32x32x16_f16(f[q],     bfrag[q],     acca, 0, 0, 0);
        accb = __builtin_amdgcn_mfma_f32_32x32x16_f16(f[q + 8], bfrag[q + 8], accb, 0, 0, 0);
      }
      __builtin_amdgcn_s_setprio(0);
    }
    { char* t = p0; p0 = p1; p1 = p2; p2 = t; }
    if (pf) { asm volatile("s_waitcnt vmcnt(4)" ::: "memory"); }
    else    { asm volatile("s_waitcnt vmcnt(0)" ::: "memory"); }
    __builtin_amdgcn_s_barrier();
    __builtin_amdgcn_sched_barrier(0);
    if (pf) {
      const char* src = cbB + (c + 1) * 32768 + 512 + laneoff + wave * 128;
      #pragma unroll
      for (int i = 0; i < 4; ++i) gload_lds16(src + i * 32, p2 + wave * 4096 + i * 1024);
    }
    {
      const char* ab = p0 + (pxl << 4) + (khalf << 9);
      h8 f[16];
      #pragma unroll
      for (int q = 0; q < 16; ++q) f[q] = *reinterpret_cast<const h8*>(ab + (q << 10));
      __builtin_amdgcn_s_setprio(1);
      #pragma unroll
      for (int q = 0; q < 8; ++q) {
        acca = __builtin_amdgcn_mfma_f32_32x32x16_f16(f[q],     bfrag[16 + q], acca, 0, 0, 0);
        accb = __builtin_amdgcn_mfma_f32_32x32x16_f16(f[q + 8], bfrag[24 + q], accb, 0, 0, 0);
      }
      __builtin_amdgcn_s_setprio(0);
    }
    { char* t = p0; p0 = p1; p1 = p2; p2 = t; }
    K1_FOLD(c)
  }
  K1_MERGE
  K1_EMIT(idx_ws, flaglist, pairlist, counters, 0)
}

// ---- K1 ablation variants (scratch-only; diagnostic) --------------------------
// M: 1=noloop 2=noread 3=nostage 4=nobar 5=nofold 6=deep(dist-3, 4 buffers)
template<int M>
__global__ __launch_bounds__(256, 2) void k1_abl(
    const float* __restrict__ z, const unsigned short* __restrict__ cb16,
    const float* __restrict__ cnp,
    int* __restrict__ idx_s, int* __restrict__ flag_s,
    unsigned long long* __restrict__ pair_s, int* __restrict__ ctr_s)
{
  extern __shared__ char smem[];
  constexpr int NBUF = (M == 6) ? 4 : 3;
  float* cn_lds = reinterpret_cast<float*>(smem + NBUF * 16384);
  K1_IDS

  if constexpr (M == 1) {   // noloop: prologue only, everything sunk
    K1_BFRAG
    float fs = 0.f;
    #pragma unroll
    for (int s = 0; s < 32; ++s) {
      #pragma unroll
      for (int e = 0; e < 8; ++e) fs += (float)bfrag[s][e];
    }
    asm volatile("" :: "v"(fs));
    if (lane < 32) idx_s[(px0 + (wave << 5) + lane) & 65535] = (int)fs;
    return;
  }

  // prologue staging
  if constexpr (M != 1) {
    #pragma unroll
    for (int i = 0; i < 4; ++i)
      gload_lds16(cbB + laneoff + wave * 128 + i * 32, smem + wave * 4096 + i * 1024);
    #pragma unroll
    for (int i = 0; i < 4; ++i)
      gload_lds16(cbB + 512 + laneoff + wave * 128 + i * 32, smem + 16384 + wave * 4096 + i * 1024);
    if constexpr (M == 6) {
      #pragma unroll
      for (int i = 0; i < 4; ++i)
        gload_lds16(cbB + 32768 + laneoff + wave * 128 + i * 32, smem + 32768 + wave * 4096 + i * 1024);
    }
  }
  K1_BFRAG
  for (int i = tid; i < 1024; i += 256) cn_lds[i] = cnp[i];
  __syncthreads();

  float v0 = INFINITY, v1 = INFINITY, v2 = INFINITY, v3 = INFINITY;
  int   i0 = 0, i1 = 0, i2 = 0, i3 = 0;
  f32x16 acca, accb;
  #pragma unroll
  for (int i = 0; i < 16; ++i) { acca[i] = 0.f; accb[i] = 0.f; }

  char* p0 = smem; char* p1 = smem + 16384; char* p2 = smem + 32768;
  char* p3 = smem + NBUF * 16384 - 16384;   // only used by M==6 (== smem+49152)

  if constexpr (M == 6) {
    // dist-3 prefetch, 4-buffer ring, counted vmcnt(8)
    for (int c = 0; c < 32; ++c) {
      #pragma unroll
      for (int h = 0; h < 2; ++h) {
        const int st = 2 * c + h;
        if (st <= 61) { asm volatile("s_waitcnt vmcnt(8)" ::: "memory"); }
        else if (st == 62) { asm volatile("s_waitcnt vmcnt(4)" ::: "memory"); }
        else { asm volatile("s_waitcnt vmcnt(0)" ::: "memory"); }
        __builtin_amdgcn_s_barrier();
        __builtin_amdgcn_sched_barrier(0);
        if (st <= 60) {
          const int st3 = st + 3;
          const char* src = cbB + (st3 >> 1) * 32768 + (st3 & 1) * 512 + laneoff + wave * 128;
          #pragma unroll
          for (int i = 0; i < 4; ++i) gload_lds16(src + i * 32, p3 + wave * 4096 + i * 1024);
        }
        {
          const char* ab = p0 + (pxl << 4) + (khalf << 9);
          h8 f[16];
          #pragma unroll
          for (int q = 0; q < 16; ++q) f[q] = *reinterpret_cast<const h8*>(ab + (q << 10));
          __builtin_amdgcn_s_setprio(1);
          if (h == 0) {
            #pragma unroll
            for (int q = 0; q < 8; ++q) {
              acca = __builtin_amdgcn_mfma_f32_32x32x16_f16(f[q],     bfrag[q],     acca, 0, 0, 0);
              accb = __builtin_amdgcn_mfma_f32_32x32x16_f16(f[q + 8], bfrag[q + 8], accb, 0, 0, 0);
            }
          } else {
            #pragma unroll
            for (int q = 0; q < 8; ++q) {
              acca = __builtin_amdgcn_mfma_f32_32x32x16_f16(f[q],     bfrag[16 + q], acca, 0, 0, 0);
              accb = __builtin_amdgcn_mfma_f32_32x32x16_f16(f[q + 8], bfrag[24 + q], accb, 0, 0, 0);
            }
          }
          __builtin_amdgcn_s_setprio(0);
        }
        { char* t = p0; p0 = p1; p1 = p2; p2 = p3; p3 = t; }
      }
      K1_FOLD(c)
    }
  } else {
    for (int c = 0; c < 32; ++c) {
      const bool pf = (c < 31);
      #pragma unroll
      for (int h = 0; h < 2; ++h) {
        if constexpr (M != 3) {
          if (pf || h == 0) { asm volatile("s_waitcnt vmcnt(4)" ::: "memory"); }
          else              { asm volatile("s_waitcnt vmcnt(0)" ::: "memory"); }
        }
        if constexpr (M != 4) {
          __builtin_amdgcn_s_barrier();
          __builtin_amdgcn_sched_barrier(0);
        }
        if constexpr (M != 3) {
          if (pf) {
            const char* src = cbB + (c + 1) * 32768 + h * 512 + laneoff + wave * 128;
            #pragma unroll
            for (int i = 0; i < 4; ++i) gload_lds16(src + i * 32, p2 + wave * 4096 + i * 1024);
          }
        }
        {
          const char* ab = p0 + (pxl << 4) + (khalf << 9);
          __builtin_amdgcn_s_setprio(1);
          if constexpr (M == 2) {   // noread: MFMA on register operands
            if (h == 0) {
              #pragma unroll
              for (int q = 0; q < 8; ++q) {
                acca = __builtin_amdgcn_mfma_f32_32x32x16_f16(bfrag[q],     bfrag[q],     acca, 0, 0, 0);
                accb = __builtin_amdgcn_mfma_f32_32x32x16_f16(bfrag[q + 8], bfrag[q + 8], accb, 0, 0, 0);
              }
            } else {
              #pragma unroll
              for (int q = 0; q < 8; ++q) {
                acca = __builtin_amdgcn_mfma_f32_32x32x16_f16(bfrag[16 + q], bfrag[16 + q], acca, 0, 0, 0);
                accb = __builtin_amdgcn_mfma_f32_32x32x16_f16(bfrag[24 + q], bfrag[24 + q], accb, 0, 0, 0);
              }
            }
          } else {
            h8 f[16];
            #pragma unroll
            for (int q = 0; q < 16; ++q) f[q] = *reinterpret_cast<const h8*>(ab + (q << 10));
            if (h == 0) {
              #pragma unroll
              for (int q = 0; q < 8; ++q) {
                acca = __builtin_amdgcn_mfma_f32_32x32x16_f16(f[q],     bfrag[q],     acca, 0, 0, 0);
                accb = __builtin_amdgcn_mfma_f32_32x32x16_f16(f[q + 8], bfrag[q + 8], accb, 0, 0, 0);
              }
            } else {
              #pragma unroll
              for (int q = 0; q < 8; ++q) {
                acca = __builtin_amdgcn_mfma_f32_32x32x16_f16(f[q],     bfrag[16 + q], acca, 0, 0, 0);
                accb = __builtin_amdgcn_mfma_f32_32x32x16_f16(f[q + 8], bfrag[24 + q], accb, 0, 0, 0);
              }
            }
          }
          __builtin_amdgcn_s_setprio(0);
        }
        { char* t = p0; p0 = p1; p1 = p2; p2 = t; }
      }
      if constexpr (M != 5) {
        K1_FOLD(c)
      }
    }
  }

  if constexpr (M == 5) {   // nofold: sink accumulators
    float fs = 0.f;
    #pragma unroll
    for (int i = 0; i < 16; ++i) fs += acca[i] + accb[i];
    asm volatile("" :: "v"(fs));
    if (lane < 32) idx_s[(px0 + (wave << 5) + lane) & 65535] = (int)fs;
    return;
  }
  K1_MERGE
  K1_EMIT(idx_s, flag_s, pair_s, ctr_s, 1)
}

// ---- K2a: exact fp64 check of <=4 candidates, one wave per pixel --------------
__global__ __launch_bounds__(256) void k2a_quad(
    const float* __restrict__ z, const float* __restrict__ cb,
    const unsigned long long* __restrict__ pairlist, const int* __restrict__ counters,
    int* __restrict__ idx_ws)
{
  const int lane = threadIdx.x & 63;
  const int wid  = (blockIdx.x << 2) + (threadIdx.x >> 6);
  const int nwav = gridDim.x << 2;
  const int nf   = counters[1];
  for (int e = wid; e < nf; e += nwav) {
    unsigned long long pk = pairlist[e];
    int pix = (int)(pk & 0xFFFFull);
    int c0 = (int)((pk >> 16) & 1023ull), c1 = (int)((pk >> 26) & 1023ull);
    int c2 = (int)((pk >> 36) & 1023ull), c3 = (int)((pk >> 46) & 1023ull);
    const float* zp = z + (size_t)(pix >> 12) * 512 * 4096 + (pix & 4095);
    double s0 = 0, s1 = 0, s2 = 0, s3 = 0;
    #pragma unroll
    for (int k = 0; k < 8; ++k) {
      int c = lane + (k << 6);
      double zv2 = 2.0 * (double)zp[(size_t)c * 4096];
      double a;
      a = (double)cb[(size_t)c0 * 512 + c]; s0 = fma(a, a - zv2, s0);
      a = (double)cb[(size_t)c1 * 512 + c]; s1 = fma(a, a - zv2, s1);
      a = (double)cb[(size_t)c2 * 512 + c]; s2 = fma(a, a - zv2, s2);
      a = (double)cb[(size_t)c3 * 512 + c]; s3 = fma(a, a - zv2, s3);
    }
    #pragma unroll
    for (int off = 32; off > 0; off >>= 1) {
      s0 += __shfl_xor(s0, off); s1 += __shfl_xor(s1, off);
      s2 += __shfl_xor(s2, off); s3 += __shfl_xor(s3, off);
    }
    double bv = s0; int bi = c0;
    if (s1 < bv || (s1 == bv && c1 < bi)) { bv = s1; bi = c1; }
    if (s2 < bv || (s2 == bv && c2 < bi)) { bv = s2; bi = c2; }
    if (s3 < bv || (s3 == bv && c3 < bi)) { bv = s3; bi = c3; }
    if (lane == 0) idx_ws[pix] = bi;
  }
}

// ---- K2b: exact fp64 full re-rank ---------------------------------------------
__global__ __launch_bounds__(256) void k2_rescan(
    const float* __restrict__ z, const float* __restrict__ cb,
    const int* __restrict__ flaglist, const int* __restrict__ counters,
    unsigned long long* __restrict__ packed_ws)
{
  __shared__ float zb[16][512];
  __shared__ unsigned long long best[16];
  __shared__ int pixl[16];
  const int t = threadIdx.x;
  const int nflag = counters[0];
  const int ntasks = ((nflag + 15) >> 4) << 2;
  for (int task = blockIdx.x; task < ntasks; task += gridDim.x) {
    const int g = task >> 2, q = task & 3;
    int rem = nflag - (g << 4);
    const int npx = rem < 16 ? rem : 16;
    if (t < 16) {
      best[t] = ~0ull;
      pixl[t] = (t < npx) ? flaglist[(g << 4) + t] : 0;
    }
    __syncthreads();
    for (int i = t; i < (npx << 9); i += 256) {
      int p = i >> 9, c = i & 511;
      int pix = pixl[p];
      zb[p][c] = z[((size_t)(pix >> 12) * 512 + c) * 4096 + (pix & 4095)];
    }
    __syncthreads();
    const int j = (q << 8) + t;
    const float* row = cb + (size_t)j * 512;
    double dot[16];
    #pragma unroll
    for (int p = 0; p < 16; ++p) dot[p] = 0.0;
    double cn = 0.0;
    for (int k = 0; k < 512; k += 4) {
      float4 cv = *(const float4*)(row + k);
      double c0 = cv.x, c1 = cv.y, c2 = cv.z, c3 = cv.w;
      cn = fma(c0, c0, cn); cn = fma(c1, c1, cn);
      cn = fma(c2, c2, cn); cn = fma(c3, c3, cn);
      #pragma unroll
      for (int p = 0; p < 16; ++p) {
        dot[p] = fma(c0, (double)zb[p][k + 0], dot[p]);
        dot[p] = fma(c1, (double)zb[p][k + 1], dot[p]);
        dot[p] = fma(c2, (double)zb[p][k + 2], dot[p]);
        dot[p] = fma(c3, (double)zb[p][k + 3], dot[p]);
      }
    }
    #pragma unroll
    for (int p = 0; p < 16; ++p) {
      if (p < npx) {
        double d = fma(-2.0, dot[p], cn);
        unsigned long long u = (unsigned long long)__double_as_longlong(d);
        u = (u >> 63) ? ~u : (u | 0x8000000000000000ull);
        unsigned long long pkk = (u & ~1023ull) | (unsigned long long)j;
        atomicMin(&best[p], pkk);
      }
    }
    __syncthreads();
    if (t < npx) atomicMin(&packed_ws[pixl[t]], best[t]);
    __syncthreads();
  }
}

// ---- K3: gather + transpose-write z_q (f32), idx (f32), loss ------------------
__global__ __launch_bounds__(256) void k3_out(
    const float* __restrict__ z, const float* __restrict__ cb,
    const int* __restrict__ idx_ws, const unsigned long long* __restrict__ packed_ws,
    float* __restrict__ out, float* __restrict__ loss_acc)
{
  extern __shared__ float rows[];
  __shared__ int idxs[32];
  __shared__ float wsum[4];
  const int t = threadIdx.x;
  const int pix0 = blockIdx.x << 5;
  const int b = pix0 >> 12, hw0 = pix0 & 4095;
  if (t < 32) {
    int pix = pix0 + t;
    int v = idx_ws[pix];
    unsigned j = (v < 0) ? (unsigned)(packed_ws[pix] & 1023ull) : (unsigned)v;
    j &= 1023u;
    idxs[t] = (int)j;
    out[OUT_IDX + pix] = (float)j;
  }
  __syncthreads();
  for (int i = t; i < 32 * 128; i += 256) {
    int r = i >> 7, kq = (i & 127) << 2;
    float4 v = *(const float4*)(cb + (size_t)idxs[r] * 512 + kq);
    float* dst = rows + r * 513 + kq;
    dst[0] = v.x; dst[1] = v.y; dst[2] = v.z; dst[3] = v.w;
  }
  __syncthreads();
  const int pl = (t & 7) << 2;
  const int cg = t >> 3;
  float acc = 0.f;
  for (int c0 = 0; c0 < 512; c0 += 32) {
    int c = c0 + cg;
    size_t go = ((size_t)(b * 512 + c)) * 4096 + hw0 + pl;
    float4 zv = *(const float4*)(z + go);
    float q0 = rows[(pl + 0) * 513 + c], q1 = rows[(pl + 1) * 513 + c];
    float q2 = rows[(pl + 2) * 513 + c], q3 = rows[(pl + 3) * 513 + c];
    float d0 = q0 - zv.x, d1 = q1 - zv.y, d2 = q2 - zv.z, d3 = q3 - zv.w;
    acc = fmaf(d0, d0, acc); acc = fmaf(d1, d1, acc);
    acc = fmaf(d2, d2, acc); acc = fmaf(d3, d3, acc);
    float4 qv;
    qv.x = zv.x + d0; qv.y = zv.y + d1;
    qv.z = zv.z + d2; qv.w = zv.w + d3;
    *reinterpret_cast<float4*>(out + go) = qv;
  }
  #pragma unroll
  for (int off = 32; off > 0; off >>= 1) acc += __shfl_down(acc, off);
  if ((t & 63) == 0) wsum[t >> 6] = acc;
  __syncthreads();
  if (t == 0) atomicAdd(loss_acc, wsum[0] + wsum[1] + wsum[2] + wsum[3]);
}

__global__ void k4_loss(const float* __restrict__ loss_acc, float* __restrict__ out)
{
  if (threadIdx.x == 0 && blockIdx.x == 0)
    out[OUT_LOSS] = loss_acc[0] * (1.25f / 33554432.f);
}

// ---- launch --------------------------------------------------------------------
extern "C" void kernel_launch(void* const* d_in, const int* in_sizes, int n_in,
                              void* d_out, int out_size, void* d_ws, size_t ws_size,
                              hipStream_t stream) {
  const float* z  = (const float*)d_in[0];
  const float* cb = (const float*)d_in[1];
  float* out = (float*)d_out;
  char* ws = (char*)d_ws;
  unsigned short*      cb16      = (unsigned short*)(ws);
  float*               cnp       = (float*)(ws + 1048576);
  int*                 idx_ws    = (int*)(ws + 1052672);
  unsigned long long*  packed_ws = (unsigned long long*)(ws + 1314816);
  int*                 flaglist  = (int*)(ws + 1839104);
  unsigned long long*  pairlist  = (unsigned long long*)(ws + 2095360);
  int*                 counters  = (int*)(ws + 2619648);   // [0..1] real, [2..13] abl
  float*               loss_acc  = (float*)(ws + 2619712);
  int*                 abl_idx   = (int*)(ws + 3145728);
  int*                 abl_flag  = (int*)(ws + 3407872);
  unsigned long long*  abl_pair  = (unsigned long long*)(ws + 3670016);

  (void)hipFuncSetAttribute((const void*)k1_main,
        hipFuncAttributeMaxDynamicSharedMemorySize, 53248);
  (void)hipFuncSetAttribute((const void*)k3_out,
        hipFuncAttributeMaxDynamicSharedMemorySize, 65664);

  k0_prep<<<1024, 64, 0, stream>>>(cb, cb16, cnp, counters, loss_acc, idx_ws, packed_ws);

  if (ws_size >= 4194304) {   // diagnostic ablations (scratch-only)
    (void)hipFuncSetAttribute((const void*)k1_abl<1>, hipFuncAttributeMaxDynamicSharedMemorySize, 53248);
    (void)hipFuncSetAttribute((const void*)k1_abl<2>, hipFuncAttributeMaxDynamicSharedMemorySize, 53248);
    (void)hipFuncSetAttribute((const void*)k1_abl<3>, hipFuncAttributeMaxDynamicSharedMemorySize, 53248);
    (void)hipFuncSetAttribute((const void*)k1_abl<4>, hipFuncAttributeMaxDynamicSharedMemorySize, 53248);
    (void)hipFuncSetAttribute((const void*)k1_abl<5>, hipFuncAttributeMaxDynamicSharedMemorySize, 53248);
    (void)hipFuncSetAttribute((const void*)k1_abl<6>, hipFuncAttributeMaxDynamicSharedMemorySize, 69632);
    k1_abl<1><<<512, 256, 53248, stream>>>(z, cb16, cnp, abl_idx, abl_flag, abl_pair, counters + 2);
    k1_abl<2><<<512, 256, 53248, stream>>>(z, cb16, cnp, abl_idx, abl_flag, abl_pair, counters + 4);
    k1_abl<3><<<512, 256, 53248, stream>>>(z, cb16, cnp, abl_idx, abl_flag, abl_pair, counters + 6);
    k1_abl<4><<<512, 256, 53248, stream>>>(z, cb16, cnp, abl_idx, abl_flag, abl_pair, counters + 8);
    k1_abl<5><<<512, 256, 53248, stream>>>(z, cb16, cnp, abl_idx, abl_flag, abl_pair, counters + 10);
    k1_abl<6><<<512, 256, 69632, stream>>>(z, cb16, cnp, abl_idx, abl_flag, abl_pair, counters + 12);
  }

  k1_main<<<512, 256, 53248, stream>>>(z, cb16, cnp, idx_ws, flaglist, pairlist, counters);
  k2a_quad<<<1024, 256, 0, stream>>>(z, cb, pairlist, counters, idx_ws);
  k2_rescan<<<256, 256, 0, stream>>>(z, cb, flaglist, counters, packed_ws);
  k3_out<<<2048, 256, 65664, stream>>>(z, cb, idx_ws, packed_ws, out, loss_acc);
  k4_loss<<<1, 1, 0, stream>>>(loss_acc, out);
}

// Round 13
// 322.398 us; speedup vs baseline: 2.5431x; 2.5431x over previous
//
#include <hip/hip_runtime.h>
#include <hip/hip_bf16.h>

// VQ-VAE vector quantizer, MI355X. z:(16,512,64,64) f32, codebook:(1024,512) f32.
// d_out f32: z_q (33554432), loss (1), idx (65536).
// R13: k1 code-split (1024 blocks = 512 px-groups x 2 cb halves, top-3 each),
// vectorized z prologue via 32KB LDS transpose, new k1m merge kernel.

typedef _Float16 h8 __attribute__((ext_vector_type(8)));
typedef _Float16 h4 __attribute__((ext_vector_type(4)));
typedef float f32x16 __attribute__((ext_vector_type(16)));

#define OUT_LOSS  33554432
#define OUT_IDX   33554433
#define MARGIN_T  0.15f
#define FLAG_CAP  16384

__device__ __forceinline__ void gload_lds16(const void* g, void* l) {
  __builtin_amdgcn_global_load_lds(
      (const __attribute__((address_space(1))) void*)g,
      (__attribute__((address_space(3))) void*)l, 16, 0, 0);
}

// sortable key: (monotone f32 bits) << 10 | idx   (keys distinct since idx distinct)
__device__ __forceinline__ unsigned long long skey(float v, unsigned idx) {
  unsigned u = __float_as_uint(v);
  u = (u >> 31) ? ~u : (u | 0x80000000u);
  return ((unsigned long long)u << 10) | idx;
}
__device__ __forceinline__ float unkey_val(unsigned long long k) {
  unsigned su = (unsigned)(k >> 10);
  unsigned bits = (su & 0x80000000u) ? (su & 0x7FFFFFFFu) : ~su;
  return __uint_as_float(bits);
}

// ---- K0: cb fp32 -> fp16, fold-ordered 0.5||c||^2 table, workspace init ------
__global__ __launch_bounds__(64) void k0_prep(
    const float* __restrict__ cb, unsigned short* __restrict__ cb16,
    float* __restrict__ cnp, int* __restrict__ counters, float* __restrict__ loss_acc,
    int* __restrict__ idx_ws, unsigned long long* __restrict__ packed_ws)
{
  const int r = blockIdx.x, l = threadIdx.x;
  const float* row = cb + (size_t)r * 512;
  float4 a  = *(const float4*)(row + l * 8);
  float4 b4 = *(const float4*)(row + l * 8 + 4);
  h8 hv;
  hv[0] = (_Float16)a.x;  hv[1] = (_Float16)a.y;  hv[2] = (_Float16)a.z;  hv[3] = (_Float16)a.w;
  hv[4] = (_Float16)b4.x; hv[5] = (_Float16)b4.y; hv[6] = (_Float16)b4.z; hv[7] = (_Float16)b4.w;
  *reinterpret_cast<h8*>(cb16 + (size_t)r * 512 + l * 8) = hv;
  float s = a.x*a.x + a.y*a.y + a.z*a.z + a.w*a.w
          + b4.x*b4.x + b4.y*b4.y + b4.z*b4.z + b4.w*b4.w;
  #pragma unroll
  for (int off = 1; off < 64; off <<= 1) s += __shfl_xor(s, off);
  if (l == 0) {
    int jr = r & 31, c = r >> 5;                  // c = global chunk 0..31
    int khalf = (jr >> 2) & 1;
    int pat = jr - (khalf << 2);
    int rr2 = (pat & 3) + ((pat >> 3) << 2);
    cnp[(c << 5) + (khalf << 4) + rr2] = 0.5f * s;
  }
  const int pix = (r << 6) + l;
  idx_ws[pix] = (int)0x80000000;
  packed_ws[pix] = ~0ull;
  if (r == 0 && l < 4) counters[l] = 0;
  if (r == 0 && l == 0) *loss_acc = 0.f;
}

// ---- K1: half-codebook scan, vectorized z prologue, top-3 per (pixel,half) ---
// 1024 blocks (pxg = bid>>1, hc = bid&1) x 256 thr (4 waves), 128 px/block.
// dynLDS = 3*16384 + 2048 = 51200 -> 3 blocks/CU.
__global__ __launch_bounds__(256, 2) void k1_main(
    const float* __restrict__ z, const unsigned short* __restrict__ cb16,
    const float* __restrict__ cnp, float4* __restrict__ partial)
{
  extern __shared__ char smem[];
  float* cn_lds = reinterpret_cast<float*>(smem + 49152);
  const int tid   = threadIdx.x;
  const int lane  = tid & 63;
  const int wave  = tid >> 6;
  const int pxl   = lane & 31;
  const int khalf = lane >> 5;
  const int bid   = blockIdx.x;
  const int pxg   = bid >> 1;
  const int hc    = bid & 1;
  const int px0   = pxg << 7;          // 128 px
  const int b     = px0 >> 12;
  const int hw0   = px0 & 4095;
  const char* cbH = reinterpret_cast<const char*>(cb16) + hc * 524288;
  const int laneoff = pxl * 1024 + khalf * 16;

  // ---- z prologue: 4 passes of [128px][128ch] fp16 transpose tile (32KB) ----
  h8 bfrag[32];
  #pragma unroll
  for (int p = 0; p < 4; ++p) {
    #pragma unroll
    for (int it = 0; it < 4; ++it) {
      const int cg  = tid >> 5;                 // 0..7
      const int cb4 = it * 32 + cg * 4;         // channel quad base in pass
      const int pq  = (tid & 31) * 4;           // pixel quad base
      const float* src = z + ((size_t)(b * 512 + p * 128 + cb4)) * 4096 + hw0 + pq;
      float4 v0 = *(const float4*)(src);
      float4 v1 = *(const float4*)(src + 4096);
      float4 v2 = *(const float4*)(src + 8192);
      float4 v3 = *(const float4*)(src + 12288);
      const float* f0 = (const float*)&v0; const float* f1 = (const float*)&v1;
      const float* f2 = (const float*)&v2; const float* f3 = (const float*)&v3;
      #pragma unroll
      for (int dp = 0; dp < 4; ++dp) {
        h4 hv;
        hv[0] = (_Float16)f0[dp]; hv[1] = (_Float16)f1[dp];
        hv[2] = (_Float16)f2[dp]; hv[3] = (_Float16)f3[dp];
        int row = pq + dp;
        int a = ((row << 8) + cb4 * 2) ^ ((row & 15) << 4);
        *reinterpret_cast<h4*>(smem + a) = hv;
      }
    }
    __syncthreads();
    {
      const int row  = (wave << 5) + pxl;
      const int sw   = (row & 15) << 4;
      const int base = (row << 8) + (khalf << 4);
      #pragma unroll
      for (int ss = 0; ss < 8; ++ss)
        bfrag[p * 8 + ss] = *reinterpret_cast<const h8*>(smem + ((base + (ss << 5)) ^ sw));
    }
    __syncthreads();
  }

  // ---- stage chunk 0 halves + cnorm half ----
  #pragma unroll
  for (int i = 0; i < 4; ++i)
    gload_lds16(cbH + laneoff + wave * 128 + i * 32, smem + wave * 4096 + i * 1024);
  #pragma unroll
  for (int i = 0; i < 4; ++i)
    gload_lds16(cbH + 512 + laneoff + wave * 128 + i * 32, smem + 16384 + wave * 4096 + i * 1024);
  for (int i = tid; i < 512; i += 256) cn_lds[i] = cnp[hc * 512 + i];
  __syncthreads();   // drains vmcnt -> 0

  float v0 = INFINITY, v1 = INFINITY, v2 = INFINITY;
  int   i0 = 0, i1 = 0, i2 = 0;
  f32x16 acca, accb;
  #pragma unroll
  for (int i = 0; i < 16; ++i) { acca[i] = 0.f; accb[i] = 0.f; }

  char* p0 = smem; char* p1 = smem + 16384; char* p2 = smem + 32768;

  for (int c = 0; c < 16; ++c) {
    const bool pf = (c < 15);
    // half 0
    asm volatile("s_waitcnt vmcnt(4)" ::: "memory");
    __builtin_amdgcn_s_barrier();
    __builtin_amdgcn_sched_barrier(0);
    if (pf) {
      const char* src = cbH + (c + 1) * 32768 + laneoff + wave * 128;
      #pragma unroll
      for (int i = 0; i < 4; ++i) gload_lds16(src + i * 32, p2 + wave * 4096 + i * 1024);
    }
    {
      const char* ab = p0 + (pxl << 4) + (khalf << 9);
      h8 f[16];
      #pragma unroll
      for (int q = 0; q < 16; ++q) f[q] = *reinterpret_cast<const h8*>(ab + (q << 10));
      __builtin_amdgcn_s_setprio(1);
      #pragma unroll
      for (int q = 0; q < 8; ++q) {
        acca = __builtin_amdgcn_mfma_f32_32x32x16_f16(f[q],     bfrag[q],     acca, 0, 0, 0);
        accb = __builtin_amdgcn_mfma_f32_32x32x16_f16(f[q + 8], bfrag[q + 8], accb, 0, 0, 0);
      }
      __builtin_amdgcn_s_setprio(0);
    }
    { char* t = p0; p0 = p1; p1 = p2; p2 = t; }
    // half 1
    if (pf) { asm volatile("s_waitcnt vmcnt(4)" ::: "memory"); }
    else    { asm volatile("s_waitcnt vmcnt(0)" ::: "memory"); }
    __builtin_amdgcn_s_barrier();
    __builtin_amdgcn_sched_barrier(0);
    if (pf) {
      const char* src = cbH + (c + 1) * 32768 + 512 + laneoff + wave * 128;
      #pragma unroll
      for (int i = 0; i < 4; ++i) gload_lds16(src + i * 32, p2 + wave * 4096 + i * 1024);
    }
    {
      const char* ab = p0 + (pxl << 4) + (khalf << 9);
      h8 f[16];
      #pragma unroll
      for (int q = 0; q < 16; ++q) f[q] = *reinterpret_cast<const h8*>(ab + (q << 10));
      __builtin_amdgcn_s_setprio(1);
      #pragma unroll
      for (int q = 0; q < 8; ++q) {
        acca = __builtin_amdgcn_mfma_f32_32x32x16_f16(f[q],     bfrag[16 + q], acca, 0, 0, 0);
        accb = __builtin_amdgcn_mfma_f32_32x32x16_f16(f[q + 8], bfrag[24 + q], accb, 0, 0, 0);
      }
      __builtin_amdgcn_s_setprio(0);
    }
    { char* t = p0; p0 = p1; p1 = p2; p2 = t; }

    // fold chunk: top-3 (local codes -> global j via hc offset)
    {
      const float* cl = cn_lds + (c << 5) + (khalf << 4);
      float4 q0 = *(const float4*)(cl);     float4 q1 = *(const float4*)(cl + 4);
      float4 q2 = *(const float4*)(cl + 8); float4 q3 = *(const float4*)(cl + 12);
      const float cn[16] = {q0.x,q0.y,q0.z,q0.w, q1.x,q1.y,q1.z,q1.w,
                            q2.x,q2.y,q2.z,q2.w, q3.x,q3.y,q3.z,q3.w};
      float sc[16];
      #pragma unroll
      for (int r = 0; r < 16; ++r) sc[r] = cn[r] - (acca[r] + accb[r]);
      float mn = sc[0];
      #pragma unroll
      for (int r = 1; r < 16; ++r) mn = fminf(mn, sc[r]);
      if (__ballot(mn < v2)) {
        const int jbase = hc * 512 + (c << 5) + (khalf << 2);
        #pragma unroll
        for (int r = 0; r < 16; ++r) {
          int j = jbase + ((r & 3) + ((r >> 2) << 3));
          float s = sc[r];
          bool c0 = s < v0, c1 = s < v1, c2 = s < v2;
          v2 = c1 ? v1 : (c2 ? s : v2);  i2 = c1 ? i1 : (c2 ? j : i2);
          v1 = c0 ? v0 : (c1 ? s : v1);  i1 = c0 ? i0 : (c1 ? j : i1);
          v0 = c0 ? s  : v0;             i0 = c0 ? j  : i0;
        }
      }
      #pragma unroll
      for (int i = 0; i < 16; ++i) { acca[i] = 0.f; accb[i] = 0.f; }
    }
  }

  // merge khalf halves: snapshot partner's top-3 BEFORE mutating ours
  {
    float ow0 = __shfl_xor(v0, 32), ow1 = __shfl_xor(v1, 32), ow2 = __shfl_xor(v2, 32);
    int   oj0 = __shfl_xor(i0, 32), oj1 = __shfl_xor(i1, 32), oj2 = __shfl_xor(i2, 32);
    const float ow[3] = {ow0, ow1, ow2};
    const int   oj[3] = {oj0, oj1, oj2};
    #pragma unroll
    for (int k = 0; k < 3; ++k) {
      float ov = ow[k]; int oi = oj[k];
      bool c0 = ov < v0, c1 = ov < v1, c2 = ov < v2;
      v2 = c1 ? v1 : (c2 ? ov : v2);  i2 = c1 ? i1 : (c2 ? oi : i2);
      v1 = c0 ? v0 : (c1 ? ov : v1);  i1 = c0 ? i0 : (c1 ? oi : i1);
      v0 = c0 ? ov : v0;              i0 = c0 ? oi : i0;
    }
  }

  if (lane < 32) {
    const int pix = px0 + (wave << 5) + lane;
    unsigned pk = (unsigned)i0 | ((unsigned)i1 << 10) | ((unsigned)i2 << 20);
    float4 out4; out4.x = v0; out4.y = v1; out4.z = v2; out4.w = __uint_as_float(pk);
    partial[hc * 65536 + pix] = out4;
  }
}

// ---- K1m: merge halves, classify, emit ----------------------------------------
struct ull2 { unsigned long long lo, hi; };
__global__ __launch_bounds__(256) void k1_merge(
    const float4* __restrict__ partial,
    int* __restrict__ idx_ws, int* __restrict__ flaglist,
    ull2* __restrict__ pairlist, int* __restrict__ counters)
{
  const int pix  = blockIdx.x * 256 + threadIdx.x;
  const int lane = threadIdx.x & 63;
  float4 A = partial[pix], B = partial[65536 + pix];
  unsigned pa = __float_as_uint(A.w), pb = __float_as_uint(B.w);
  unsigned ia0 = pa & 1023u, ia1 = (pa >> 10) & 1023u, ia2 = (pa >> 20) & 1023u;
  unsigned ib0 = pb & 1023u, ib1 = (pb >> 10) & 1023u, ib2 = (pb >> 20) & 1023u;
  unsigned long long k0 = skey(A.x, ia0), k1 = skey(A.y, ia1), k2 = skey(A.z, ia2);
  unsigned long long k3 = skey(B.x, ib0), k4 = skey(B.y, ib1), k5 = skey(B.z, ib2);
  unsigned long long m0 = k0;
  m0 = k1 < m0 ? k1 : m0; m0 = k2 < m0 ? k2 : m0;
  m0 = k3 < m0 ? k3 : m0; m0 = k4 < m0 ? k4 : m0; m0 = k5 < m0 ? k5 : m0;
  unsigned long long m1 = ~0ull;
  unsigned long long t;
  t = (k0 == m0) ? ~0ull : k0; m1 = t < m1 ? t : m1;
  t = (k1 == m0) ? ~0ull : k1; m1 = t < m1 ? t : m1;
  t = (k2 == m0) ? ~0ull : k2; m1 = t < m1 ? t : m1;
  t = (k3 == m0) ? ~0ull : k3; m1 = t < m1 ? t : m1;
  t = (k4 == m0) ? ~0ull : k4; m1 = t < m1 ? t : m1;
  t = (k5 == m0) ? ~0ull : k5; m1 = t < m1 ? t : m1;
  float w0 = unkey_val(m0), w1 = unkey_val(m1);
  int   i0 = (int)(m0 & 1023ull);
  float cert = fminf(A.z, B.z);
  bool sane = (w0 == w0) && (w1 == w1) && (cert == cert);
  bool unfl = sane && (w1 - w0 >= MARGIN_T);
  bool hex  = sane && !unfl && (cert - w0 >= MARGIN_T);
  bool full = !unfl && !hex;
  idx_ws[pix] = unfl ? i0 : (int)0x80000000;

  unsigned long long qm = __ballot(hex);
  if (qm) {
    int leader = __ffsll(qm) - 1;
    int base = 0;
    if (lane == leader) base = atomicAdd(&counters[1], __popcll(qm));
    base = __shfl(base, leader);
    if (hex) {
      int pos = __popcll(qm & ((1ull << lane) - 1ull));
      ull2 e;
      e.lo = (unsigned long long)(unsigned)pix
           | ((unsigned long long)ia0 << 32) | ((unsigned long long)ia1 << 42)
           | ((unsigned long long)ia2 << 52);
      e.hi = (unsigned long long)ib0 | ((unsigned long long)ib1 << 10)
           | ((unsigned long long)ib2 << 20);
      pairlist[base + pos] = e;
    }
  }
  unsigned long long fm = __ballot(full);
  if (fm) {
    int leader = __ffsll(fm) - 1;
    int base = 0;
    if (lane == leader) base = atomicAdd(&counters[0], __popcll(fm));
    base = __shfl(base, leader);
    if (full) {
      int pos = __popcll(fm & ((1ull << lane) - 1ull));
      int wi = base + pos;
      if (wi < FLAG_CAP) flaglist[wi] = pix;
    }
  }
}

// ---- K2a: exact fp64 check of 6 candidates, one wave per pixel ----------------
__global__ __launch_bounds__(256) void k2a_hex(
    const float* __restrict__ z, const float* __restrict__ cb,
    const ull2* __restrict__ pairlist, const int* __restrict__ counters,
    int* __restrict__ idx_ws)
{
  const int lane = threadIdx.x & 63;
  const int wid  = (blockIdx.x << 2) + (threadIdx.x >> 6);
  const int nwav = gridDim.x << 2;
  const int nf   = counters[1];
  for (int e = wid; e < nf; e += nwav) {
    ull2 pk = pairlist[e];
    int pix = (int)(pk.lo & 0xFFFFFFFFull);
    int c0 = (int)((pk.lo >> 32) & 1023ull), c1 = (int)((pk.lo >> 42) & 1023ull);
    int c2 = (int)((pk.lo >> 52) & 1023ull);
    int c3 = (int)(pk.hi & 1023ull), c4 = (int)((pk.hi >> 10) & 1023ull);
    int c5 = (int)((pk.hi >> 20) & 1023ull);
    const float* zp = z + (size_t)(pix >> 12) * 512 * 4096 + (pix & 4095);
    double s0 = 0, s1 = 0, s2 = 0, s3 = 0, s4 = 0, s5 = 0;
    #pragma unroll
    for (int k = 0; k < 8; ++k) {
      int c = lane + (k << 6);
      double zv2 = 2.0 * (double)zp[(size_t)c * 4096];
      double a;
      a = (double)cb[(size_t)c0 * 512 + c]; s0 = fma(a, a - zv2, s0);
      a = (double)cb[(size_t)c1 * 512 + c]; s1 = fma(a, a - zv2, s1);
      a = (double)cb[(size_t)c2 * 512 + c]; s2 = fma(a, a - zv2, s2);
      a = (double)cb[(size_t)c3 * 512 + c]; s3 = fma(a, a - zv2, s3);
      a = (double)cb[(size_t)c4 * 512 + c]; s4 = fma(a, a - zv2, s4);
      a = (double)cb[(size_t)c5 * 512 + c]; s5 = fma(a, a - zv2, s5);
    }
    #pragma unroll
    for (int off = 32; off > 0; off >>= 1) {
      s0 += __shfl_xor(s0, off); s1 += __shfl_xor(s1, off);
      s2 += __shfl_xor(s2, off); s3 += __shfl_xor(s3, off);
      s4 += __shfl_xor(s4, off); s5 += __shfl_xor(s5, off);
    }
    double bv = s0; int bi = c0;
    if (s1 < bv || (s1 == bv && c1 < bi)) { bv = s1; bi = c1; }
    if (s2 < bv || (s2 == bv && c2 < bi)) { bv = s2; bi = c2; }
    if (s3 < bv || (s3 == bv && c3 < bi)) { bv = s3; bi = c3; }
    if (s4 < bv || (s4 == bv && c4 < bi)) { bv = s4; bi = c4; }
    if (s5 < bv || (s5 == bv && c5 < bi)) { bv = s5; bi = c5; }
    if (lane == 0) idx_ws[pix] = bi;
  }
}

// ---- K2b: exact fp64 full re-rank (rare) ---------------------------------------
__global__ __launch_bounds__(256) void k2_rescan(
    const float* __restrict__ z, const float* __restrict__ cb,
    const int* __restrict__ flaglist, const int* __restrict__ counters,
    unsigned long long* __restrict__ packed_ws)
{
  __shared__ float zb[16][512];
  __shared__ unsigned long long best[16];
  __shared__ int pixl[16];
  const int t = threadIdx.x;
  int nflag = counters[0];
  if (nflag > FLAG_CAP) nflag = FLAG_CAP;
  const int ntasks = ((nflag + 15) >> 4) << 2;
  for (int task = blockIdx.x; task < ntasks; task += gridDim.x) {
    const int g = task >> 2, q = task & 3;
    int rem = nflag - (g << 4);
    const int npx = rem < 16 ? rem : 16;
    if (t < 16) {
      best[t] = ~0ull;
      pixl[t] = (t < npx) ? flaglist[(g << 4) + t] : 0;
    }
    __syncthreads();
    for (int i = t; i < (npx << 9); i += 256) {
      int p = i >> 9, c = i & 511;
      int pix = pixl[p];
      zb[p][c] = z[((size_t)(pix >> 12) * 512 + c) * 4096 + (pix & 4095)];
    }
    __syncthreads();
    const int j = (q << 8) + t;
    const float* row = cb + (size_t)j * 512;
    double dot[16];
    #pragma unroll
    for (int p = 0; p < 16; ++p) dot[p] = 0.0;
    double cn = 0.0;
    for (int k = 0; k < 512; k += 4) {
      float4 cv = *(const float4*)(row + k);
      double c0 = cv.x, c1 = cv.y, c2 = cv.z, c3 = cv.w;
      cn = fma(c0, c0, cn); cn = fma(c1, c1, cn);
      cn = fma(c2, c2, cn); cn = fma(c3, c3, cn);
      #pragma unroll
      for (int p = 0; p < 16; ++p) {
        dot[p] = fma(c0, (double)zb[p][k + 0], dot[p]);
        dot[p] = fma(c1, (double)zb[p][k + 1], dot[p]);
        dot[p] = fma(c2, (double)zb[p][k + 2], dot[p]);
        dot[p] = fma(c3, (double)zb[p][k + 3], dot[p]);
      }
    }
    #pragma unroll
    for (int p = 0; p < 16; ++p) {
      if (p < npx) {
        double d = fma(-2.0, dot[p], cn);
        unsigned long long u = (unsigned long long)__double_as_longlong(d);
        u = (u >> 63) ? ~u : (u | 0x8000000000000000ull);
        unsigned long long pkk = (u & ~1023ull) | (unsigned long long)j;
        atomicMin(&best[p], pkk);
      }
    }
    __syncthreads();
    if (t < npx) atomicMin(&packed_ws[pixl[t]], best[t]);
    __syncthreads();
  }
}

// ---- K3: gather + transpose-write z_q (f32), idx (f32), loss ------------------
__global__ __launch_bounds__(256) void k3_out(
    const float* __restrict__ z, const float* __restrict__ cb,
    const int* __restrict__ idx_ws, const unsigned long long* __restrict__ packed_ws,
    float* __restrict__ out, float* __restrict__ loss_acc)
{
  extern __shared__ float rows[];
  __shared__ int idxs[32];
  __shared__ float wsum[4];
  const int t = threadIdx.x;
  const int pix0 = blockIdx.x << 5;
  const int b = pix0 >> 12, hw0 = pix0 & 4095;
  if (t < 32) {
    int pix = pix0 + t;
    int v = idx_ws[pix];
    unsigned j = (v < 0) ? (unsigned)(packed_ws[pix] & 1023ull) : (unsigned)v;
    j &= 1023u;
    idxs[t] = (int)j;
    out[OUT_IDX + pix] = (float)j;
  }
  __syncthreads();
  for (int i = t; i < 32 * 128; i += 256) {
    int r = i >> 7, kq = (i & 127) << 2;
    float4 v = *(const float4*)(cb + (size_t)idxs[r] * 512 + kq);
    float* dst = rows + r * 513 + kq;
    dst[0] = v.x; dst[1] = v.y; dst[2] = v.z; dst[3] = v.w;
  }
  __syncthreads();
  const int pl = (t & 7) << 2;
  const int cg = t >> 3;
  float acc = 0.f;
  for (int c0 = 0; c0 < 512; c0 += 32) {
    int c = c0 + cg;
    size_t go = ((size_t)(b * 512 + c)) * 4096 + hw0 + pl;
    float4 zv = *(const float4*)(z + go);
    float q0 = rows[(pl + 0) * 513 + c], q1 = rows[(pl + 1) * 513 + c];
    float q2 = rows[(pl + 2) * 513 + c], q3 = rows[(pl + 3) * 513 + c];
    float d0 = q0 - zv.x, d1 = q1 - zv.y, d2 = q2 - zv.z, d3 = q3 - zv.w;
    acc = fmaf(d0, d0, acc); acc = fmaf(d1, d1, acc);
    acc = fmaf(d2, d2, acc); acc = fmaf(d3, d3, acc);
    float4 qv;
    qv.x = zv.x + d0; qv.y = zv.y + d1;
    qv.z = zv.z + d2; qv.w = zv.w + d3;
    *reinterpret_cast<float4*>(out + go) = qv;
  }
  #pragma unroll
  for (int off = 32; off > 0; off >>= 1) acc += __shfl_down(acc, off);
  if ((t & 63) == 0) wsum[t >> 6] = acc;
  __syncthreads();
  if (t == 0) atomicAdd(loss_acc, wsum[0] + wsum[1] + wsum[2] + wsum[3]);
}

__global__ void k4_loss(const float* __restrict__ loss_acc, float* __restrict__ out)
{
  if (threadIdx.x == 0 && blockIdx.x == 0)
    out[OUT_LOSS] = loss_acc[0] * (1.25f / 33554432.f);
}

// ---- launch --------------------------------------------------------------------
extern "C" void kernel_launch(void* const* d_in, const int* in_sizes, int n_in,
                              void* d_out, int out_size, void* d_ws, size_t ws_size,
                              hipStream_t stream) {
  const float* z  = (const float*)d_in[0];
  const float* cb = (const float*)d_in[1];
  float* out = (float*)d_out;
  char* ws = (char*)d_ws;
  // layout (fits 4 MB): pairlist overlays cb16 (dead after k1)
  unsigned short*      cb16      = (unsigned short*)(ws);                 // 1 MB
  ull2*                pairlist  = (ull2*)(ws);                           // overlay
  float4*              partial   = (float4*)(ws + 1048576);               // 2 MB
  int*                 idx_ws    = (int*)(ws + 3145728);                  // 256 KB
  unsigned long long*  packed_ws = (unsigned long long*)(ws + 3407872);   // 512 KB
  int*                 flaglist  = (int*)(ws + 3932160);                  // 64 KB
  float*               cnp       = (float*)(ws + 3997696);                // 4 KB
  int*                 counters  = (int*)(ws + 4001792);                  // 64 B
  float*               loss_acc  = (float*)(ws + 4001856);

  (void)hipFuncSetAttribute((const void*)k1_main,
        hipFuncAttributeMaxDynamicSharedMemorySize, 51200);
  (void)hipFuncSetAttribute((const void*)k3_out,
        hipFuncAttributeMaxDynamicSharedMemorySize, 65664);

  k0_prep<<<1024, 64, 0, stream>>>(cb, cb16, cnp, counters, loss_acc, idx_ws, packed_ws);
  k1_main<<<1024, 256, 51200, stream>>>(z, cb16, cnp, partial);
  k1_merge<<<256, 256, 0, stream>>>(partial, idx_ws, flaglist, pairlist, counters);
  k2a_hex<<<1024, 256, 0, stream>>>(z, cb, pairlist, counters, idx_ws);
  k2_rescan<<<256, 256, 0, stream>>>(z, cb, flaglist, counters, packed_ws);
  k3_out<<<2048, 256, 65664, stream>>>(z, cb, idx_ws, packed_ws, out, loss_acc);
  k4_loss<<<1, 1, 0, stream>>>(loss_acc, out);
}

// Round 14
// 177.862 us; speedup vs baseline: 4.6097x; 1.8126x over previous
//
#include <hip/hip_runtime.h>
#include <hip/hip_bf16.h>

// VQ-VAE vector quantizer, MI355X. z:(16,512,64,64) f32, codebook:(1024,512) f32.
// d_out f32: z_q (33554432), loss (1), idx (65536).
// R14 = R11 flow, but: cbT fragment-stream layout (coalesced staging) +
// vectorized z-prologue via swizzled LDS transpose tile.

typedef _Float16 h8 __attribute__((ext_vector_type(8)));
typedef float f32x16 __attribute__((ext_vector_type(16)));

#define OUT_LOSS  33554432
#define OUT_IDX   33554433
#define MARGIN_T  0.15f

__device__ __forceinline__ void gload_lds16(const void* g, void* l) {
  __builtin_amdgcn_global_load_lds(
      (const __attribute__((address_space(1))) void*)g,
      (__attribute__((address_space(3))) void*)l, 16, 0, 0);
}

__device__ __forceinline__ int zswz(int row) {
  return ((row & 3) << 6) | (((row >> 2) & 3) << 4);
}

// ---- K0: cb fp32 -> fp16 FRAGMENT-STREAM cbT + fold-ordered 0.5||c||^2 -------
// cbT byte (c*32+s)*1024 + (hk*32+rr)*16 holds channels [s*16+hk*8, +8) of code
// row c*32+rr. A stage (c,h) is a CONTIGUOUS 16KB: coalesced gload_lds in k1.
__global__ __launch_bounds__(64) void k0_prep(
    const float* __restrict__ cb, unsigned short* __restrict__ cbT,
    float* __restrict__ cnp, int* __restrict__ counters, float* __restrict__ loss_acc,
    int* __restrict__ idx_ws, unsigned long long* __restrict__ packed_ws)
{
  const int r = blockIdx.x, l = threadIdx.x;
  const float* row = cb + (size_t)r * 512;
  float4 a  = *(const float4*)(row + l * 8);
  float4 b4 = *(const float4*)(row + l * 8 + 4);
  h8 hv;
  hv[0] = (_Float16)a.x;  hv[1] = (_Float16)a.y;  hv[2] = (_Float16)a.z;  hv[3] = (_Float16)a.w;
  hv[4] = (_Float16)b4.x; hv[5] = (_Float16)b4.y; hv[6] = (_Float16)b4.z; hv[7] = (_Float16)b4.w;
  {
    const int c  = r >> 5, rr = r & 31;
    const int s  = l >> 1;                    // k-slot (16 channels)
    const int hk = l & 1;                     // k-half within slot
    char* dst = reinterpret_cast<char*>(cbT)
              + (size_t)(c * 32 + s) * 1024 + (hk * 32 + rr) * 16;
    *reinterpret_cast<h8*>(dst) = hv;
  }
  float s = a.x*a.x + a.y*a.y + a.z*a.z + a.w*a.w
          + b4.x*b4.x + b4.y*b4.y + b4.z*b4.z + b4.w*b4.w;
  #pragma unroll
  for (int off = 1; off < 64; off <<= 1) s += __shfl_xor(s, off);
  if (l == 0) {
    int jr = r & 31, c = r >> 5;
    int khalf = (jr >> 2) & 1;
    int pat = jr - (khalf << 2);
    int rr2 = (pat & 3) + ((pat >> 3) << 2);
    cnp[(c << 5) + (khalf << 4) + rr2] = 0.5f * s;
  }
  const int pix = (r << 6) + l;                // 1024x64 == 65536
  idx_ws[pix] = (int)0x80000000;
  packed_ws[pix] = ~0ull;
  if (r == 0 && l < 4) counters[l] = 0;
  if (r == 0 && l == 0) *loss_acc = 0.f;
}

// ---- K1: fp16 MFMA scan — coalesced staging + vectorized z prologue ----------
// 512 blocks x 256 thr (4 waves), 128 px/block. dynLDS = 3*16384 + 4096 = 53248.
__global__ __launch_bounds__(256, 2) void k1_main(
    const float* __restrict__ z, const unsigned short* __restrict__ cbT,
    const float* __restrict__ cnp,
    int* __restrict__ idx_ws, int* __restrict__ flaglist,
    unsigned long long* __restrict__ pairlist, int* __restrict__ counters)
{
  extern __shared__ char smem[];
  float* cn_lds = reinterpret_cast<float*>(smem + 49152);
  const int tid   = threadIdx.x;
  const int lane  = tid & 63;
  const int wave  = tid >> 6;          // 0..3
  const int pxl   = lane & 31;
  const int khalf = lane >> 5;
  const int px0   = blockIdx.x << 7;   // 128 px/block
  const int b     = px0 >> 12;
  const int hw0   = px0 & 4095;
  const char* cbB = reinterpret_cast<const char*>(cbT);

  // ---- z prologue: 4 passes of [128 px][128 ch] fp16 tile in smem[0..32K) ----
  // write: thread covers 8 ch x 4 px x 2; read: h8 fragments, 2-way-free banks.
  h8 bfrag[32];
  for (int i = tid; i < 1024; i += 256) cn_lds[i] = cnp[i];
  #pragma unroll
  for (int p = 0; p < 4; ++p) {
    #pragma unroll
    for (int it2 = 0; it2 < 2; ++it2) {
      const int cg  = tid >> 5;                    // 0..7
      const int ch0 = it2 * 64 + cg * 8;           // 8-channel base (local)
      const int pq  = (tid & 31) * 4;              // pixel quad base
      const float* src = z + ((size_t)(b * 512 + p * 128 + ch0)) * 4096 + hw0 + pq;
      float4 v[8];
      #pragma unroll
      for (int j = 0; j < 8; ++j) v[j] = *(const float4*)(src + (size_t)j * 4096);
      const float* vf = reinterpret_cast<const float*>(v);
      #pragma unroll
      for (int dp = 0; dp < 4; ++dp) {
        h8 hv;
        #pragma unroll
        for (int j = 0; j < 8; ++j) hv[j] = (_Float16)vf[j * 4 + dp];
        int row = pq + dp;
        int a = (row << 8) + ch0 * 2;
        a ^= zswz(row);
        *reinterpret_cast<h8*>(smem + a) = hv;
      }
    }
    __syncthreads();
    {
      const int row  = (wave << 5) + pxl;
      const int sw   = zswz(row);
      const int base = (row << 8) + (khalf << 4);
      #pragma unroll
      for (int ss = 0; ss < 8; ++ss)
        bfrag[p * 8 + ss] = *reinterpret_cast<const h8*>(smem + ((base + (ss << 5)) ^ sw));
    }
    __syncthreads();
  }

  // ---- stage chunk 0 (both halves): CONTIGUOUS 16KB copies, coalesced -------
  #pragma unroll
  for (int i = 0; i < 4; ++i)
    gload_lds16(cbB + tid * 16 + i * 4096, smem + tid * 16 + i * 4096);
  #pragma unroll
  for (int i = 0; i < 4; ++i)
    gload_lds16(cbB + 16384 + tid * 16 + i * 4096, smem + 16384 + tid * 16 + i * 4096);
  __syncthreads();   // drains ALL vmem: vmcnt = 0 here

  float v0 = INFINITY, v1 = INFINITY, v2 = INFINITY, v3 = INFINITY;
  int   i0 = 0, i1 = 0, i2 = 0, i3 = 0;
  f32x16 acca, accb;
  #pragma unroll
  for (int i = 0; i < 16; ++i) { acca[i] = 0.f; accb[i] = 0.f; }

  char* p0 = smem;            // current half-stage
  char* p1 = smem + 16384;    // next half-stage
  char* p2 = smem + 32768;    // staging target (current + 2)

  for (int c = 0; c < 32; ++c) {
    const bool pf = (c < 31);
    // ---- half h=0: compute from p0; stage (c+1,h0) -> p2 ----
    asm volatile("s_waitcnt vmcnt(4)" ::: "memory");
    __builtin_amdgcn_s_barrier();
    __builtin_amdgcn_sched_barrier(0);
    if (pf) {
      const char* src = cbB + (c + 1) * 32768 + tid * 16;
      #pragma unroll
      for (int i = 0; i < 4; ++i)
        gload_lds16(src + i * 4096, p2 + tid * 16 + i * 4096);
    }
    {
      const char* ab = p0 + (khalf << 9) + (pxl << 4);
      h8 f[16];
      #pragma unroll
      for (int q = 0; q < 16; ++q) f[q] = *reinterpret_cast<const h8*>(ab + (q << 10));
      __builtin_amdgcn_s_setprio(1);
      #pragma unroll
      for (int q = 0; q < 8; ++q) {
        acca = __builtin_amdgcn_mfma_f32_32x32x16_f16(f[q],     bfrag[q],     acca, 0, 0, 0);
        accb = __builtin_amdgcn_mfma_f32_32x32x16_f16(f[q + 8], bfrag[q + 8], accb, 0, 0, 0);
      }
      __builtin_amdgcn_s_setprio(0);
    }
    { char* t = p0; p0 = p1; p1 = p2; p2 = t; }
    // ---- half h=1: compute from p0; stage (c+1,h1) -> p2 ----
    if (pf) { asm volatile("s_waitcnt vmcnt(4)" ::: "memory"); }
    else    { asm volatile("s_waitcnt vmcnt(0)" ::: "memory"); }
    __builtin_amdgcn_s_barrier();
    __builtin_amdgcn_sched_barrier(0);
    if (pf) {
      const char* src = cbB + (c + 1) * 32768 + 16384 + tid * 16;
      #pragma unroll
      for (int i = 0; i < 4; ++i)
        gload_lds16(src + i * 4096, p2 + tid * 16 + i * 4096);
    }
    {
      const char* ab = p0 + (khalf << 9) + (pxl << 4);
      h8 f[16];
      #pragma unroll
      for (int q = 0; q < 16; ++q) f[q] = *reinterpret_cast<const h8*>(ab + (q << 10));
      __builtin_amdgcn_s_setprio(1);
      #pragma unroll
      for (int q = 0; q < 8; ++q) {
        acca = __builtin_amdgcn_mfma_f32_32x32x16_f16(f[q],     bfrag[16 + q], acca, 0, 0, 0);
        accb = __builtin_amdgcn_mfma_f32_32x32x16_f16(f[q + 8], bfrag[24 + q], accb, 0, 0, 0);
      }
      __builtin_amdgcn_s_setprio(0);
    }
    { char* t = p0; p0 = p1; p1 = p2; p2 = t; }

    // ---- fold chunk c: scores, min-tree filter, rare branch-free insert -----
    {
      const float* cl = cn_lds + (c << 5) + (khalf << 4);
      float4 q0 = *(const float4*)(cl);     float4 q1 = *(const float4*)(cl + 4);
      float4 q2 = *(const float4*)(cl + 8); float4 q3 = *(const float4*)(cl + 12);
      const float cn[16] = {q0.x,q0.y,q0.z,q0.w, q1.x,q1.y,q1.z,q1.w,
                            q2.x,q2.y,q2.z,q2.w, q3.x,q3.y,q3.z,q3.w};
      float sc[16];
      #pragma unroll
      for (int r = 0; r < 16; ++r) sc[r] = cn[r] - (acca[r] + accb[r]);
      float mn = sc[0];
      #pragma unroll
      for (int r = 1; r < 16; ++r) mn = fminf(mn, sc[r]);
      if (__ballot(mn < v3)) {
        const int jbase = (c << 5) + (khalf << 2);
        #pragma unroll
        for (int r = 0; r < 16; ++r) {
          int j = jbase + ((r & 3) + ((r >> 2) << 3));
          float s = sc[r];
          bool c0 = s < v0, c1 = s < v1, c2 = s < v2, c3 = s < v3;
          v3 = c2 ? v2 : (c3 ? s : v3);  i3 = c2 ? i2 : (c3 ? j : i3);
          v2 = c1 ? v1 : (c2 ? s : v2);  i2 = c1 ? i1 : (c2 ? j : i2);
          v1 = c0 ? v0 : (c1 ? s : v1);  i1 = c0 ? i0 : (c1 ? j : i1);
          v0 = c0 ? s  : v0;             i0 = c0 ? j  : i0;
        }
      }
      #pragma unroll
      for (int i = 0; i < 16; ++i) { acca[i] = 0.f; accb[i] = 0.f; }
    }
  }

  // merge khalf halves: snapshot partner's full list BEFORE mutating ours
  {
    float ow0 = __shfl_xor(v0, 32), ow1 = __shfl_xor(v1, 32),
          ow2 = __shfl_xor(v2, 32), ow3 = __shfl_xor(v3, 32);
    int   oj0 = __shfl_xor(i0, 32), oj1 = __shfl_xor(i1, 32),
          oj2 = __shfl_xor(i2, 32), oj3 = __shfl_xor(i3, 32);
    const float ow[4] = {ow0, ow1, ow2, ow3};
    const int   oj[4] = {oj0, oj1, oj2, oj3};
    #pragma unroll
    for (int k = 0; k < 4; ++k) {
      float ov = ow[k]; int oi = oj[k];
      bool c0 = ov < v0, c1 = ov < v1, c2 = ov < v2, c3 = ov < v3;
      v3 = c2 ? v2 : (c3 ? ov : v3);  i3 = c2 ? i2 : (c3 ? oi : i3);
      v2 = c1 ? v1 : (c2 ? ov : v2);  i2 = c1 ? i1 : (c2 ? oi : i2);
      v1 = c0 ? v0 : (c1 ? ov : v1);  i1 = c0 ? i0 : (c1 ? oi : i1);
      v0 = c0 ? ov : v0;              i0 = c0 ? oi : i0;
    }
  }

  const int pix = px0 + (wave << 5) + lane;   // valid for lane<32 only
  bool sane = (v0 == v0) && (v3 == v3) && ((unsigned)i0 < 1024u);
  bool unfl = sane && (v1 - v0 >= MARGIN_T);
  bool quad = sane && !unfl && (v3 - v0 >= MARGIN_T);
  bool qpred = (lane < 32) && quad;
  bool fpred = (lane < 32) && !unfl && !quad;
  if (lane < 32) idx_ws[pix] = unfl ? i0 : (int)0x80000000;

  unsigned long long qm = __ballot(qpred);
  if (qm) {
    int leader = __ffsll(qm) - 1;
    int base = 0;
    if (lane == leader) base = atomicAdd(&counters[1], __popcll(qm));
    base = __shfl(base, leader);
    if (qpred) {
      int pos = __popcll(qm & ((1ull << lane) - 1ull));
      pairlist[base + pos] = (unsigned long long)(unsigned)pix
          | ((unsigned long long)(unsigned)i0 << 16)
          | ((unsigned long long)(unsigned)i1 << 26)
          | ((unsigned long long)(unsigned)i2 << 36)
          | ((unsigned long long)(unsigned)i3 << 46);
    }
  }
  unsigned long long fm = __ballot(fpred);
  if (fm) {
    int leader = __ffsll(fm) - 1;
    int base = 0;
    if (lane == leader) base = atomicAdd(&counters[0], __popcll(fm));
    base = __shfl(base, leader);
    if (fpred) {
      int pos = __popcll(fm & ((1ull << lane) - 1ull));
      flaglist[base + pos] = pix;
    }
  }
}

// ---- K2a: exact fp64 check of <=4 candidates, one wave per pixel --------------
__global__ __launch_bounds__(256) void k2a_quad(
    const float* __restrict__ z, const float* __restrict__ cb,
    const unsigned long long* __restrict__ pairlist, const int* __restrict__ counters,
    int* __restrict__ idx_ws)
{
  const int lane = threadIdx.x & 63;
  const int wid  = (blockIdx.x << 2) + (threadIdx.x >> 6);
  const int nwav = gridDim.x << 2;
  const int nf   = counters[1];
  for (int e = wid; e < nf; e += nwav) {
    unsigned long long pk = pairlist[e];
    int pix = (int)(pk & 0xFFFFull);
    int c0 = (int)((pk >> 16) & 1023ull), c1 = (int)((pk >> 26) & 1023ull);
    int c2 = (int)((pk >> 36) & 1023ull), c3 = (int)((pk >> 46) & 1023ull);
    const float* zp = z + (size_t)(pix >> 12) * 512 * 4096 + (pix & 4095);
    double s0 = 0, s1 = 0, s2 = 0, s3 = 0;
    #pragma unroll
    for (int k = 0; k < 8; ++k) {
      int c = lane + (k << 6);
      double zv2 = 2.0 * (double)zp[(size_t)c * 4096];
      double a;
      a = (double)cb[(size_t)c0 * 512 + c]; s0 = fma(a, a - zv2, s0);
      a = (double)cb[(size_t)c1 * 512 + c]; s1 = fma(a, a - zv2, s1);
      a = (double)cb[(size_t)c2 * 512 + c]; s2 = fma(a, a - zv2, s2);
      a = (double)cb[(size_t)c3 * 512 + c]; s3 = fma(a, a - zv2, s3);
    }
    #pragma unroll
    for (int off = 32; off > 0; off >>= 1) {
      s0 += __shfl_xor(s0, off); s1 += __shfl_xor(s1, off);
      s2 += __shfl_xor(s2, off); s3 += __shfl_xor(s3, off);
    }
    double bv = s0; int bi = c0;
    if (s1 < bv || (s1 == bv && c1 < bi)) { bv = s1; bi = c1; }
    if (s2 < bv || (s2 == bv && c2 < bi)) { bv = s2; bi = c2; }
    if (s3 < bv || (s3 == bv && c3 < bi)) { bv = s3; bi = c3; }
    if (lane == 0) idx_ws[pix] = bi;
  }
}

// ---- K2b: exact fp64 full re-rank (rare: >=4 codes within margin) -------------
__global__ __launch_bounds__(256) void k2_rescan(
    const float* __restrict__ z, const float* __restrict__ cb,
    const int* __restrict__ flaglist, const int* __restrict__ counters,
    unsigned long long* __restrict__ packed_ws)
{
  __shared__ float zb[16][512];
  __shared__ unsigned long long best[16];
  __shared__ int pixl[16];
  const int t = threadIdx.x;
  const int nflag = counters[0];
  const int ntasks = ((nflag + 15) >> 4) << 2;
  for (int task = blockIdx.x; task < ntasks; task += gridDim.x) {
    const int g = task >> 2, q = task & 3;
    int rem = nflag - (g << 4);
    const int npx = rem < 16 ? rem : 16;
    if (t < 16) {
      best[t] = ~0ull;
      pixl[t] = (t < npx) ? flaglist[(g << 4) + t] : 0;
    }
    __syncthreads();
    for (int i = t; i < (npx << 9); i += 256) {
      int p = i >> 9, c = i & 511;
      int pix = pixl[p];
      zb[p][c] = z[((size_t)(pix >> 12) * 512 + c) * 4096 + (pix & 4095)];
    }
    __syncthreads();
    const int j = (q << 8) + t;
    const float* row = cb + (size_t)j * 512;
    double dot[16];
    #pragma unroll
    for (int p = 0; p < 16; ++p) dot[p] = 0.0;
    double cn = 0.0;
    for (int k = 0; k < 512; k += 4) {
      float4 cv = *(const float4*)(row + k);
      double c0 = cv.x, c1 = cv.y, c2 = cv.z, c3 = cv.w;
      cn = fma(c0, c0, cn); cn = fma(c1, c1, cn);
      cn = fma(c2, c2, cn); cn = fma(c3, c3, cn);
      #pragma unroll
      for (int p = 0; p < 16; ++p) {
        dot[p] = fma(c0, (double)zb[p][k + 0], dot[p]);
        dot[p] = fma(c1, (double)zb[p][k + 1], dot[p]);
        dot[p] = fma(c2, (double)zb[p][k + 2], dot[p]);
        dot[p] = fma(c3, (double)zb[p][k + 3], dot[p]);
      }
    }
    #pragma unroll
    for (int p = 0; p < 16; ++p) {
      if (p < npx) {
        double d = fma(-2.0, dot[p], cn);
        unsigned long long u = (unsigned long long)__double_as_longlong(d);
        u = (u >> 63) ? ~u : (u | 0x8000000000000000ull);
        unsigned long long pkk = (u & ~1023ull) | (unsigned long long)j;
        atomicMin(&best[p], pkk);
      }
    }
    __syncthreads();
    if (t < npx) atomicMin(&packed_ws[pixl[t]], best[t]);
    __syncthreads();
  }
}

// ---- K3: gather + transpose-write z_q (f32), idx (f32), loss ------------------
__global__ __launch_bounds__(256) void k3_out(
    const float* __restrict__ z, const float* __restrict__ cb,
    const int* __restrict__ idx_ws, const unsigned long long* __restrict__ packed_ws,
    float* __restrict__ out, float* __restrict__ loss_acc)
{
  extern __shared__ float rows[];
  __shared__ int idxs[32];
  __shared__ float wsum[4];
  const int t = threadIdx.x;
  const int pix0 = blockIdx.x << 5;
  const int b = pix0 >> 12, hw0 = pix0 & 4095;
  if (t < 32) {
    int pix = pix0 + t;
    int v = idx_ws[pix];
    unsigned j = (v < 0) ? (unsigned)(packed_ws[pix] & 1023ull) : (unsigned)v;
    j &= 1023u;
    idxs[t] = (int)j;
    out[OUT_IDX + pix] = (float)j;
  }
  __syncthreads();
  for (int i = t; i < 32 * 128; i += 256) {
    int r = i >> 7, kq = (i & 127) << 2;
    float4 v = *(const float4*)(cb + (size_t)idxs[r] * 512 + kq);
    float* dst = rows + r * 513 + kq;
    dst[0] = v.x; dst[1] = v.y; dst[2] = v.z; dst[3] = v.w;
  }
  __syncthreads();
  const int pl = (t & 7) << 2;
  const int cg = t >> 3;
  float acc = 0.f;
  for (int c0 = 0; c0 < 512; c0 += 32) {
    int c = c0 + cg;
    size_t go = ((size_t)(b * 512 + c)) * 4096 + hw0 + pl;
    float4 zv = *(const float4*)(z + go);
    float q0 = rows[(pl + 0) * 513 + c], q1 = rows[(pl + 1) * 513 + c];
    float q2 = rows[(pl + 2) * 513 + c], q3 = rows[(pl + 3) * 513 + c];
    float d0 = q0 - zv.x, d1 = q1 - zv.y, d2 = q2 - zv.z, d3 = q3 - zv.w;
    acc = fmaf(d0, d0, acc); acc = fmaf(d1, d1, acc);
    acc = fmaf(d2, d2, acc); acc = fmaf(d3, d3, acc);
    float4 qv;
    qv.x = zv.x + d0; qv.y = zv.y + d1;
    qv.z = zv.z + d2; qv.w = zv.w + d3;
    *reinterpret_cast<float4*>(out + go) = qv;
  }
  #pragma unroll
  for (int off = 32; off > 0; off >>= 1) acc += __shfl_down(acc, off);
  if ((t & 63) == 0) wsum[t >> 6] = acc;
  __syncthreads();
  if (t == 0) atomicAdd(loss_acc, wsum[0] + wsum[1] + wsum[2] + wsum[3]);
}

__global__ void k4_loss(const float* __restrict__ loss_acc, float* __restrict__ out)
{
  if (threadIdx.x == 0 && blockIdx.x == 0)
    out[OUT_LOSS] = loss_acc[0] * (1.25f / 33554432.f);
}

// ---- launch --------------------------------------------------------------------
extern "C" void kernel_launch(void* const* d_in, const int* in_sizes, int n_in,
                              void* d_out, int out_size, void* d_ws, size_t ws_size,
                              hipStream_t stream) {
  const float* z  = (const float*)d_in[0];
  const float* cb = (const float*)d_in[1];
  float* out = (float*)d_out;
  char* ws = (char*)d_ws;
  unsigned short*      cbT       = (unsigned short*)(ws);                 // 1 MB
  float*               cnp       = (float*)(ws + 1048576);                // 4 KB
  int*                 idx_ws    = (int*)(ws + 1052672);                  // 256 KB
  unsigned long long*  packed_ws = (unsigned long long*)(ws + 1314816);   // 512 KB
  int*                 flaglist  = (int*)(ws + 1839104);                  // 256 KB
  unsigned long long*  pairlist  = (unsigned long long*)(ws + 2095360);   // 512 KB
  int*                 counters  = (int*)(ws + 2619648);
  float*               loss_acc  = (float*)(ws + 2619712);

  (void)hipFuncSetAttribute((const void*)k1_main,
        hipFuncAttributeMaxDynamicSharedMemorySize, 53248);
  (void)hipFuncSetAttribute((const void*)k3_out,
        hipFuncAttributeMaxDynamicSharedMemorySize, 65664);

  k0_prep<<<1024, 64, 0, stream>>>(cb, cbT, cnp, counters, loss_acc, idx_ws, packed_ws);
  k1_main<<<512, 256, 53248, stream>>>(z, cbT, cnp, idx_ws, flaglist, pairlist, counters);
  k2a_quad<<<1024, 256, 0, stream>>>(z, cb, pairlist, counters, idx_ws);
  k2_rescan<<<256, 256, 0, stream>>>(z, cb, flaglist, counters, packed_ws);
  k3_out<<<2048, 256, 65664, stream>>>(z, cb, idx_ws, packed_ws, out, loss_acc);
  k4_loss<<<1, 1, 0, stream>>>(loss_acc, out);
}